// Round 21
// baseline (373.582 us; speedup 1.0000x reference)
//
#include <hip/hip_runtime.h>

// ---------- types ----------
typedef short s16x8 __attribute__((ext_vector_type(8)));   // 8 bf16 (4 VGPRs)
typedef float f32x4 __attribute__((ext_vector_type(4)));

static __device__ __forceinline__ unsigned short f2bf(float f) {
  unsigned u = __builtin_bit_cast(unsigned, f);
  return (unsigned short)((u + 0x7FFFu + ((u >> 16) & 1u)) >> 16);   // RNE; finite
}

// async global->LDS, 16B per lane; LDS dst is wave-uniform base + lane*16
#define GLL16(G, L) __builtin_amdgcn_global_load_lds( \
    (const __attribute__((address_space(1))) void*)(G), \
    (__attribute__((address_space(3))) void*)(L), 16, 0, 0)

#define KD 512
// B=16, T=512, C=19, E=512, H=8, HD=64; groups = 8192, rows = 155648 = 1024*152.
// Afb layout: half-block hb (152 rows, padded to 160 = 10 frags of 16 rows);
// frag (hb, f, kt) = 1 KB at ((hb*10 + f)*16 + kt)*512 shorts; within-frag lane
// lf = (row&15) + 16*jc holds 16 B of [row][kt*32 + jc*8]. Reads lane*16-linear.

// ---------- kernel: eeg fp32 -> bf16 half-block fragment layout ----------
__global__ __launch_bounds__(256)
void k_conva(const float* __restrict__ src, unsigned short* __restrict__ dst) {
  long gid = (long)blockIdx.x * 256 + threadIdx.x;   // 10,485,760 threads
  int lane = (int)(gid & 63);
  long rest = gid >> 6;
  int kt = (int)(rest & 15); rest >>= 4;
  int f  = (int)(rest % 10);
  int hb = (int)(rest / 10);
  int row_l = f * 16 + (lane & 15);
  int jc = lane >> 4;
  s16x8 o = (s16x8){0, 0, 0, 0, 0, 0, 0, 0};
  if (row_l < 152) {                       // pad rows 152..159 zeroed (never scored)
    const float* p = src + ((long)hb * 152 + row_l) * KD + kt * 32 + jc * 8;
    float4 v0 = *(const float4*)p;
    float4 v1 = *(const float4*)(p + 4);
    o[0]=(short)f2bf(v0.x); o[1]=(short)f2bf(v0.y); o[2]=(short)f2bf(v0.z); o[3]=(short)f2bf(v0.w);
    o[4]=(short)f2bf(v1.x); o[5]=(short)f2bf(v1.y); o[6]=(short)f2bf(v1.z); o[7]=(short)f2bf(v1.w);
  }
  *(s16x8*)(dst + gid * 8) = o;            // fully coalesced 16 B/lane
}

// ---------- kernel: weights fp32 -> bf16 fragment layout (rows 0..511 wq, 512..1023 wk) ----------
__global__ __launch_bounds__(256)
void k_convw(const float* __restrict__ wq, const float* __restrict__ wk,
             unsigned short* __restrict__ Wf) {
  int gid = blockIdx.x * 256 + threadIdx.x;   // 65536 threads
  int nt = gid >> 10, slot = gid & 1023;
  int kt = slot >> 6, lf = slot & 63;
  int f  = nt * 16 + (lf & 15);
  int jc = lf >> 4;
  const float* p = ((f < 512) ? (wq + (long)f * KD) : (wk + (long)(f - 512) * KD)) + kt * 32 + jc * 8;
  float4 v0 = *(const float4*)p;
  float4 v1 = *(const float4*)(p + 4);
  s16x8 o;
  o[0]=(short)f2bf(v0.x); o[1]=(short)f2bf(v0.y); o[2]=(short)f2bf(v0.z); o[3]=(short)f2bf(v0.w);
  o[4]=(short)f2bf(v1.x); o[5]=(short)f2bf(v1.y); o[6]=(short)f2bf(v1.z); o[7]=(short)f2bf(v1.w);
  *(s16x8*)(Wf + ((long)nt * 16 + kt) * 512 + (long)lf * 8) = o;
}

// CL access: 160 rows x 128 shorts (256 B stride), XOR-swizzled byte ^= (row&7)<<4.
#define CL_RD(ROW, CSH) (*(const s16x8*)((const char*)CL + (ROW) * 256 + ((((CSH) * 2)) ^ ((((ROW) & 7)) << 4))))
#define CL_WR(ROW, CSH, V) (*(unsigned short*)((char*)CL + (ROW) * 256 + ((((CSH) * 2)) ^ ((((ROW) & 7)) << 4))) = (V))

// ---------- fused kernel: projection GEMM + scores + softmax, 8 groups / block ----------
// v4 (R21): depth-2 counted-vmcnt pipeline WITHOUT the occupancy confound that
// killed R13: BK=32, 16 K-steps, 3 staging buffers of 18 KB (54 KB, CL 40 KB
// unioned inside) -> still 2 blocks/CU. STAGE(t+2) issued at top of step t;
// end-of-step s_waitcnt vmcnt(nslot) (wave-uniform 3 or 2, never 0 until drain)
// + raw s_barrier. Each batch flies ~2 compute phases before being waited ->
// barrier drain ~0 (was the residual ~30% stall at depth-1).
__global__ __launch_bounds__(512, 4)
void k_fgemm(const unsigned short* __restrict__ Af, const unsigned short* __restrict__ Wf,
             const float* __restrict__ bq, const float* __restrict__ bk,
             float* __restrict__ oacc) {
  __shared__ unsigned short SL[27648];   // 55,296 B: 3 x 9216-short staging bufs; CL alias
  __shared__ float red[8];
  unsigned short* CL = SL;               // alias (valid after post-loop barrier)

  const int tid  = threadIdx.x;
  const int lane = tid & 63;
  const int wid  = tid >> 6;        // 0..7
  const int wm   = wid >> 2;        // 0..1: owns m-frags wm*5 .. wm*5+4
  const int wn   = wid & 3;         // 0..3: owns n-frags wn*2, wn*2+1
  const int rlo  = lane & 15, rhi = lane >> 4;

  // XCD-chunked swizzle: grid 8192 (%8==0, bijective); h fastest -> the 8 head-
  // blocks of one hb run temporally adjacent on ONE XCD (A panel L2-resident).
  const int cpx = gridDim.x >> 3;
  const int L   = ((int)blockIdx.x & 7) * cpx + ((int)blockIdx.x >> 3);
  const int hb  = L >> 3;           // 0..1023
  const int h   = L & 7;

  // ---- staging slots (BK=32): slot s = frag fi (0..17), 1 KB each; wave wid owns
  // s ∈ {wid, wid+8, wid+16(if wid<2)}. Global addr advances +512 shorts per step.
  const unsigned short* gp0; const unsigned short* gp1; const unsigned short* gp2 = 0;
  unsigned int lo0, lo1, lo2 = 0;
#define SLOT_INIT(S, GP, LO) do { \
    int fi = (S); \
    if (fi < 10) { \
      GP = Af + ((long)(hb * 10 + fi) * 16) * 512 + lane * 8; \
    } else { \
      int ns = fi - 10; \
      int nt = (ns < 4) ? (h * 4 + ns) : (32 + h * 4 + (ns - 4)); \
      GP = Wf + ((long)nt * 16) * 512 + lane * 8; \
    } \
    LO = (S) * 512; \
  } while (0)
  SLOT_INIT(wid, gp0, lo0);
  SLOT_INIT(wid + 8, gp1, lo1);
  if (wid < 2) SLOT_INIT(wid + 16, gp2, lo2);
#undef SLOT_INIT

#define STAGE(BUFOFF) do { \
    GLL16(gp0, SL + (BUFOFF) + lo0); gp0 += 512; \
    GLL16(gp1, SL + (BUFOFF) + lo1); gp1 += 512; \
    if (wid < 2) { GLL16(gp2, SL + (BUFOFF) + lo2); gp2 += 512; } \
  } while (0)

  // counted wait: own t+1 batch done (t+2's nslot still outstanding)
#define WAITN() do { \
    if (wid < 2) asm volatile("s_waitcnt vmcnt(3)" ::: "memory"); \
    else         asm volatile("s_waitcnt vmcnt(2)" ::: "memory"); \
  } while (0)

  // ---- pre-load epilogue biases (latency hidden under K-loop) ----
  float biasv[2];
#pragma unroll
  for (int n = 0; n < 2; ++n) {
    int nf = wn * 2 + n;
    int c  = nf * 16 + rlo;
    biasv[n] = (nf < 4) ? bq[h * 64 + c] : bk[h * 64 + (c - 64)];
  }

  f32x4 acc[5][2] = {};
  STAGE(0);          // batch t0
  STAGE(9216);       // batch t1
  WAITN();           // t0 landed; t1 flying
  asm volatile("s_barrier" ::: "memory");

  int cur = 0;
#pragma unroll 1
  for (int t = 0; t < 16; ++t) {
    if (t < 14) {
      int stg = cur + 2; if (stg >= 3) stg -= 3;
      STAGE(stg * 9216);               // flies across 2 compute phases
    }
    const unsigned short* bufp = SL + cur * 9216;

    s16x8 bf0 = *(const s16x8*)(bufp + (10 + wn * 2) * 512 + lane * 8);
    s16x8 bf1 = *(const s16x8*)(bufp + (10 + wn * 2 + 1) * 512 + lane * 8);
    s16x8 af0 = *(const s16x8*)(bufp + (wm * 5 + 0) * 512 + lane * 8);
    s16x8 af1 = *(const s16x8*)(bufp + (wm * 5 + 1) * 512 + lane * 8);
    s16x8 af2 = *(const s16x8*)(bufp + (wm * 5 + 2) * 512 + lane * 8);
    s16x8 af3 = *(const s16x8*)(bufp + (wm * 5 + 3) * 512 + lane * 8);
    s16x8 af4 = *(const s16x8*)(bufp + (wm * 5 + 4) * 512 + lane * 8);
    __builtin_amdgcn_s_setprio(1);
    acc[0][0] = __builtin_amdgcn_mfma_f32_16x16x32_bf16(af0, bf0, acc[0][0], 0, 0, 0);
    acc[0][1] = __builtin_amdgcn_mfma_f32_16x16x32_bf16(af0, bf1, acc[0][1], 0, 0, 0);
    acc[1][0] = __builtin_amdgcn_mfma_f32_16x16x32_bf16(af1, bf0, acc[1][0], 0, 0, 0);
    acc[1][1] = __builtin_amdgcn_mfma_f32_16x16x32_bf16(af1, bf1, acc[1][1], 0, 0, 0);
    acc[2][0] = __builtin_amdgcn_mfma_f32_16x16x32_bf16(af2, bf0, acc[2][0], 0, 0, 0);
    acc[2][1] = __builtin_amdgcn_mfma_f32_16x16x32_bf16(af2, bf1, acc[2][1], 0, 0, 0);
    acc[3][0] = __builtin_amdgcn_mfma_f32_16x16x32_bf16(af3, bf0, acc[3][0], 0, 0, 0);
    acc[3][1] = __builtin_amdgcn_mfma_f32_16x16x32_bf16(af3, bf1, acc[3][1], 0, 0, 0);
    acc[4][0] = __builtin_amdgcn_mfma_f32_16x16x32_bf16(af4, bf0, acc[4][0], 0, 0, 0);
    acc[4][1] = __builtin_amdgcn_mfma_f32_16x16x32_bf16(af4, bf1, acc[4][1], 0, 0, 0);
    __builtin_amdgcn_s_setprio(0);

    if (t < 15) {
      if (t < 14) WAITN();                                 // t+1 done; t+2 flying
      else        asm volatile("s_waitcnt vmcnt(0)" ::: "memory");   // final drain
      asm volatile("s_barrier" ::: "memory");
    }
    cur += 1; if (cur >= 3) cur -= 3;
  }
#undef STAGE
#undef WAITN
  __syncthreads();   // all waves done reading SL -> safe to overwrite as CL

  // ---- C -> CL (bias + bf16, swizzled); rows fi*16+rhi*4+j < 160 ----
#pragma unroll
  for (int n = 0; n < 2; ++n) {
    int c = (wn * 2 + n) * 16 + rlo;
#pragma unroll
    for (int i = 0; i < 5; ++i) {
      int rbase = (wm * 5 + i) * 16 + rhi * 4;
#pragma unroll
      for (int j = 0; j < 4; ++j)
        CL_WR(rbase + j, c, f2bf(acc[i][n][j] + biasv[n]));
    }
  }
  __syncthreads();

  // ---- scores + softmax (verified v3 math): wave wid = group wid ----
  float psum = 0.f;
  {
    const int g19 = wid * 19;        // rows g19 .. g19+18 (max 151)
    const s16x8 z8 = {};
    f32x4 s[2][2] = {};              // [k-tile mi][q-tile nj]
#pragma unroll
    for (int ks = 0; ks < 2; ++ks) {
      s16x8 kb[2], qa[2];
#pragma unroll
      for (int mi = 0; mi < 2; ++mi) {
        int r = mi * 16 + rlo;
        kb[mi] = (r < 19) ? CL_RD(g19 + r, 64 + ks * 32 + rhi * 8) : z8;
        qa[mi] = (r < 19) ? CL_RD(g19 + r, ks * 32 + rhi * 8) : z8;
      }
#pragma unroll
      for (int mi = 0; mi < 2; ++mi)
#pragma unroll
        for (int nj = 0; nj < 2; ++nj)
          s[mi][nj] = __builtin_amdgcn_mfma_f32_16x16x32_bf16(kb[mi], qa[nj], s[mi][nj], 0, 0, 0);
    }
    // lane view: q = nj*16 + rlo; k = mi*16 + rhi*4 + j
#pragma unroll
    for (int nj = 0; nj < 2; ++nj) {
      const int q = nj * 16 + rlo;
      const bool qv = (q < 19);
      const bool wv = (rhi == 0);          // k=16..18 live on rhi==0 (j<3)
      float v0 = s[0][nj][0] * 0.125f;
      float v1 = s[0][nj][1] * 0.125f;
      float v2 = s[0][nj][2] * 0.125f;
      float v3 = s[0][nj][3] * 0.125f;
      float w0 = s[1][nj][0] * 0.125f;
      float w1 = s[1][nj][1] * 0.125f;
      float w2 = s[1][nj][2] * 0.125f;
      float mm = fmaxf(fmaxf(v0, v1), fmaxf(v2, v3));
      if (wv) mm = fmaxf(mm, fmaxf(fmaxf(w0, w1), w2));
      mm = fmaxf(mm, __shfl_xor(mm, 16));
      mm = fmaxf(mm, __shfl_xor(mm, 32));
      float e0 = __expf(v0 - mm), e1 = __expf(v1 - mm);
      float e2 = __expf(v2 - mm), e3 = __expf(v3 - mm);
      float se = e0 + e1 + e2 + e3;
      int k0 = rhi * 4;
      float ue = ((k0 > q) ? e0 : 0.f) + ((k0 + 1 > q) ? e1 : 0.f)
               + ((k0 + 2 > q) ? e2 : 0.f) + ((k0 + 3 > q) ? e3 : 0.f);
      if (wv) {
        float f0 = __expf(w0 - mm), f1 = __expf(w1 - mm), f2 = __expf(w2 - mm);
        se += f0 + f1 + f2;
        ue += ((16 > q) ? f0 : 0.f) + ((17 > q) ? f1 : 0.f) + ((18 > q) ? f2 : 0.f);
      }
      se += __shfl_xor(se, 16); se += __shfl_xor(se, 32);
      ue += __shfl_xor(ue, 16); ue += __shfl_xor(ue, 32);
      if (qv && rhi == 0) psum += ue / se;
    }
  }

  psum += __shfl_xor(psum, 1);
  psum += __shfl_xor(psum, 2);
  psum += __shfl_xor(psum, 4);
  psum += __shfl_xor(psum, 8);
  psum += __shfl_xor(psum, 16);
  psum += __shfl_xor(psum, 32);
  if (lane == 0) red[wid] = psum;
  __syncthreads();
  if (tid == 0) {
    // all 8 groups of this block share batch b = (hb*8)/512 = hb>>6
    atomicAdd(&oacc[hb >> 6], red[0] + red[1] + red[2] + red[3]
                            + red[4] + red[5] + red[6] + red[7]);
  }
}

// ---------- kernel: finalize out[b] = clip(acc[b] / (8*171*512), 0, 1) ----------
__global__ void k_fin(const float* __restrict__ acc, float* __restrict__ out) {
  int t = threadIdx.x;
  if (t < 16) {
    float v = acc[t] * (1.0f / 700416.0f);
    out[t] = fminf(1.0f, fmaxf(0.0f, v));
  }
}

// ---------- host ----------
extern "C" void kernel_launch(void* const* d_in, const int* in_sizes, int n_in,
                              void* d_out, int out_size, void* d_ws, size_t ws_size,
                              hipStream_t stream) {
  const float* eeg = (const float*)d_in[0];
  const float* wq  = (const float*)d_in[1];
  const float* wk  = (const float*)d_in[2];
  const float* bq  = (const float*)d_in[3];
  const float* bk  = (const float*)d_in[4];
  float* out = (float*)d_out;

  char* ws = (char*)d_ws;
  unsigned short* Wf  = (unsigned short*)ws;                       // 1 MiB weights
  float* acc          = (float*)(ws + (1 << 20));                  // 64 B accumulators
  unsigned short* Afb = (unsigned short*)(ws + (1 << 20) + 256);   // 167.8 MB frag eeg

  hipMemsetAsync(acc, 0, 64, stream);
  k_convw<<<256, 256, 0, stream>>>(wq, wk, Wf);
  k_conva<<<40960, 256, 0, stream>>>(eeg, Afb);   // 1024 hb x 10 f x 16 kt frags
  k_fgemm<<<8192, 512, 0, stream>>>(Afb, Wf, bq, bk, acc);
  k_fin<<<1, 64, 0, stream>>>(acc, out);
}

// Round 22
// 316.308 us; speedup vs baseline: 1.1811x; 1.1811x over previous
//
#include <hip/hip_runtime.h>

// ---------- types ----------
typedef short s16x8 __attribute__((ext_vector_type(8)));   // 8 bf16 (4 VGPRs)
typedef float f32x4 __attribute__((ext_vector_type(4)));

static __device__ __forceinline__ unsigned short f2bf(float f) {
  unsigned u = __builtin_bit_cast(unsigned, f);
  return (unsigned short)((u + 0x7FFFu + ((u >> 16) & 1u)) >> 16);   // RNE; finite
}

// async global->LDS, 16B per lane; LDS dst is wave-uniform base + lane*16
#define GLL16(G, L) __builtin_amdgcn_global_load_lds( \
    (const __attribute__((address_space(1))) void*)(G), \
    (__attribute__((address_space(3))) void*)(L), 16, 0, 0)

#define KD 512
// B=16, T=512, C=19, E=512, H=8, HD=64; groups = 8192, rows = 155648 = 1024*152.
// Afb layout: half-block hb (152 rows, padded to 160 = 10 frags of 16 rows);
// frag (hb, f, kt) = 1 KB at ((hb*10 + f)*16 + kt)*512 shorts; within-frag lane
// lf = (row&15) + 16*jc holds 16 B of [row][kt*32 + jc*8]. Reads lane*16-linear.

// ---------- kernel: eeg fp32 -> bf16 half-block fragment layout ----------
__global__ __launch_bounds__(256)
void k_conva(const float* __restrict__ src, unsigned short* __restrict__ dst) {
  long gid = (long)blockIdx.x * 256 + threadIdx.x;   // 10,485,760 threads
  int lane = (int)(gid & 63);
  long rest = gid >> 6;
  int kt = (int)(rest & 15); rest >>= 4;
  int f  = (int)(rest % 10);
  int hb = (int)(rest / 10);
  int row_l = f * 16 + (lane & 15);
  int jc = lane >> 4;
  s16x8 o = (s16x8){0, 0, 0, 0, 0, 0, 0, 0};
  if (row_l < 152) {                       // pad rows 152..159 zeroed (never scored)
    const float* p = src + ((long)hb * 152 + row_l) * KD + kt * 32 + jc * 8;
    float4 v0 = *(const float4*)p;
    float4 v1 = *(const float4*)(p + 4);
    o[0]=(short)f2bf(v0.x); o[1]=(short)f2bf(v0.y); o[2]=(short)f2bf(v0.z); o[3]=(short)f2bf(v0.w);
    o[4]=(short)f2bf(v1.x); o[5]=(short)f2bf(v1.y); o[6]=(short)f2bf(v1.z); o[7]=(short)f2bf(v1.w);
  }
  *(s16x8*)(dst + gid * 8) = o;            // fully coalesced 16 B/lane
}

// ---------- kernel: weights fp32 -> bf16 fragment layout (rows 0..511 wq, 512..1023 wk) ----------
__global__ __launch_bounds__(256)
void k_convw(const float* __restrict__ wq, const float* __restrict__ wk,
             unsigned short* __restrict__ Wf) {
  int gid = blockIdx.x * 256 + threadIdx.x;   // 65536 threads
  int nt = gid >> 10, slot = gid & 1023;
  int kt = slot >> 6, lf = slot & 63;
  int f  = nt * 16 + (lf & 15);
  int jc = lf >> 4;
  const float* p = ((f < 512) ? (wq + (long)f * KD) : (wk + (long)(f - 512) * KD)) + kt * 32 + jc * 8;
  float4 v0 = *(const float4*)p;
  float4 v1 = *(const float4*)(p + 4);
  s16x8 o;
  o[0]=(short)f2bf(v0.x); o[1]=(short)f2bf(v0.y); o[2]=(short)f2bf(v0.z); o[3]=(short)f2bf(v0.w);
  o[4]=(short)f2bf(v1.x); o[5]=(short)f2bf(v1.y); o[6]=(short)f2bf(v1.z); o[7]=(short)f2bf(v1.w);
  *(s16x8*)(Wf + ((long)nt * 16 + kt) * 512 + (long)lf * 8) = o;
}

// CL access: 160 rows x 128 shorts (256 B stride), XOR-swizzled byte ^= (row&7)<<4.
// Written by VALU stores, read by ds_read (both swizzled: rule-21 clean).
#define CL_RD(ROW, CSH) (*(const s16x8*)((const char*)CL + (ROW) * 256 + ((((CSH) * 2)) ^ ((((ROW) & 7)) << 4))))
#define CL_WR(ROW, CSH, V) (*(unsigned short*)((char*)CL + (ROW) * 256 + ((((CSH) * 2)) ^ ((((ROW) & 7)) << 4))) = (V))

// ---------- fused kernel: projection GEMM + scores + softmax, 8 groups / block ----------
// FINAL (R20 config, best measured = 316.7 us total): BK=64, 8 K-steps, 1 barrier
// per step; LDS union (staging 73.7 KB reused as CL) -> 2 blocks/CU; hoisted
// per-slot staging pointers (+1024 shorts/step); static slot counts; setprio(1)
// around MFMA clusters; pre-loaded biases. Falsified levers (measured): higher
// occupancy (R15/R16), counted-vmcnt (R13/R21), LDS-BW diet (R14), reg-staged A
// (R11), 256^2 8-phase (R16).
__global__ __launch_bounds__(512, 4)
void k_fgemm(const unsigned short* __restrict__ Af, const unsigned short* __restrict__ Wf,
             const float* __restrict__ bq, const float* __restrict__ bk,
             float* __restrict__ oacc) {
  __shared__ unsigned short SL[36864];   // 73,728 B: Sbuf[2][36*512] union CL[160*128]
  __shared__ float red[8];
  unsigned short* CL = SL;               // alias (valid after post-loop barrier)

  const int tid  = threadIdx.x;
  const int lane = tid & 63;
  const int wid  = tid >> 6;        // 0..7
  const int wm   = wid >> 2;        // 0..1: owns m-frags wm*5 .. wm*5+4
  const int wn   = wid & 3;         // 0..3: owns n-frags wn*2, wn*2+1
  const int rlo  = lane & 15, rhi = lane >> 4;

  // XCD-chunked swizzle: grid 8192 (%8==0, bijective); h fastest -> the 8 head-
  // blocks of one hb run temporally adjacent on ONE XCD (A panel L2-resident).
  const int cpx = gridDim.x >> 3;
  const int L   = ((int)blockIdx.x & 7) * cpx + ((int)blockIdx.x >> 3);
  const int hb  = L >> 3;           // 0..1023
  const int h   = L & 7;

  // ---- hoisted staging slots: wave wid owns s = wid + 8k (k < nslot) ----
  // slot s: fi = s>>1 (0..9 A-frag, 10..17 B-frag), half = s&1; per K-step the
  // global address advances by exactly 1024 shorts (2 KB). Static indices only.
  const unsigned short* gp0; const unsigned short* gp1; const unsigned short* gp2;
  const unsigned short* gp3; const unsigned short* gp4 = 0;
  unsigned int lo0, lo1, lo2, lo3, lo4 = 0;
#define SLOT_INIT(K, GP, LO) do { \
    int s = wid + 8 * (K); \
    int fi = s >> 1, half = s & 1; \
    if (fi < 10) { \
      GP = Af + ((long)(hb * 10 + fi) * 16 + half) * 512 + lane * 8; \
    } else { \
      int ns = fi - 10; \
      int nt = (ns < 4) ? (h * 4 + ns) : (32 + h * 4 + (ns - 4)); \
      GP = Wf + ((long)nt * 16 + half) * 512 + lane * 8; \
    } \
    LO = s * 512; \
  } while (0)
  SLOT_INIT(0, gp0, lo0);
  SLOT_INIT(1, gp1, lo1);
  SLOT_INIT(2, gp2, lo2);
  SLOT_INIT(3, gp3, lo3);
  if (wid < 4) SLOT_INIT(4, gp4, lo4);
#undef SLOT_INIT

#define STAGE(BUFOFF) do { \
    GLL16(gp0, SL + (BUFOFF) + lo0); gp0 += 1024; \
    GLL16(gp1, SL + (BUFOFF) + lo1); gp1 += 1024; \
    GLL16(gp2, SL + (BUFOFF) + lo2); gp2 += 1024; \
    GLL16(gp3, SL + (BUFOFF) + lo3); gp3 += 1024; \
    if (wid < 4) { GLL16(gp4, SL + (BUFOFF) + lo4); gp4 += 1024; } \
  } while (0)

  // ---- pre-load epilogue biases (latency hidden under K-loop) ----
  float biasv[2];
#pragma unroll
  for (int n = 0; n < 2; ++n) {
    int nf = wn * 2 + n;
    int c  = nf * 16 + rlo;
    biasv[n] = (nf < 4) ? bq[h * 64 + c] : bk[h * 64 + (c - 64)];
  }

  f32x4 acc[5][2] = {};
  STAGE(0);
  __syncthreads();   // vmcnt(0) drain: buf0 ready

#pragma unroll 1
  for (int t = 0; t < 8; ++t) {
    const int curoff = (t & 1) * 18432;
    if (t < 7) STAGE(curoff ^ 18432);   // issue next buffer; flies across 40 MFMA
    const unsigned short* bufp = SL + curoff;

#pragma unroll
    for (int hh = 0; hh < 2; ++hh) {
      s16x8 bf0 = *(const s16x8*)(bufp + ((10 + wn * 2) * 2 + hh) * 512 + lane * 8);
      s16x8 bf1 = *(const s16x8*)(bufp + ((10 + wn * 2 + 1) * 2 + hh) * 512 + lane * 8);
      s16x8 af0 = *(const s16x8*)(bufp + ((wm * 5 + 0) * 2 + hh) * 512 + lane * 8);
      s16x8 af1 = *(const s16x8*)(bufp + ((wm * 5 + 1) * 2 + hh) * 512 + lane * 8);
      s16x8 af2 = *(const s16x8*)(bufp + ((wm * 5 + 2) * 2 + hh) * 512 + lane * 8);
      s16x8 af3 = *(const s16x8*)(bufp + ((wm * 5 + 3) * 2 + hh) * 512 + lane * 8);
      s16x8 af4 = *(const s16x8*)(bufp + ((wm * 5 + 4) * 2 + hh) * 512 + lane * 8);
      __builtin_amdgcn_s_setprio(1);
      acc[0][0] = __builtin_amdgcn_mfma_f32_16x16x32_bf16(af0, bf0, acc[0][0], 0, 0, 0);
      acc[0][1] = __builtin_amdgcn_mfma_f32_16x16x32_bf16(af0, bf1, acc[0][1], 0, 0, 0);
      acc[1][0] = __builtin_amdgcn_mfma_f32_16x16x32_bf16(af1, bf0, acc[1][0], 0, 0, 0);
      acc[1][1] = __builtin_amdgcn_mfma_f32_16x16x32_bf16(af1, bf1, acc[1][1], 0, 0, 0);
      acc[2][0] = __builtin_amdgcn_mfma_f32_16x16x32_bf16(af2, bf0, acc[2][0], 0, 0, 0);
      acc[2][1] = __builtin_amdgcn_mfma_f32_16x16x32_bf16(af2, bf1, acc[2][1], 0, 0, 0);
      acc[3][0] = __builtin_amdgcn_mfma_f32_16x16x32_bf16(af3, bf0, acc[3][0], 0, 0, 0);
      acc[3][1] = __builtin_amdgcn_mfma_f32_16x16x32_bf16(af3, bf1, acc[3][1], 0, 0, 0);
      acc[4][0] = __builtin_amdgcn_mfma_f32_16x16x32_bf16(af4, bf0, acc[4][0], 0, 0, 0);
      acc[4][1] = __builtin_amdgcn_mfma_f32_16x16x32_bf16(af4, bf1, acc[4][1], 0, 0, 0);
      __builtin_amdgcn_s_setprio(0);
    }
    if (t < 7) __syncthreads();
  }
#undef STAGE
  __syncthreads();   // all waves done reading SL -> safe to overwrite as CL

  // ---- C -> CL (bias + bf16, swizzled); rows fi*16+rhi*4+j < 160 ----
#pragma unroll
  for (int n = 0; n < 2; ++n) {
    int c = (wn * 2 + n) * 16 + rlo;
#pragma unroll
    for (int i = 0; i < 5; ++i) {
      int rbase = (wm * 5 + i) * 16 + rhi * 4;
#pragma unroll
      for (int j = 0; j < 4; ++j)
        CL_WR(rbase + j, c, f2bf(acc[i][n][j] + biasv[n]));
    }
  }
  __syncthreads();

  // ---- scores + softmax (verified v3 math): wave wid = group wid ----
  float psum = 0.f;
  {
    const int g19 = wid * 19;        // rows g19 .. g19+18 (max 151)
    const s16x8 z8 = {};
    f32x4 s[2][2] = {};              // [k-tile mi][q-tile nj]
#pragma unroll
    for (int ks = 0; ks < 2; ++ks) {
      s16x8 kb[2], qa[2];
#pragma unroll
      for (int mi = 0; mi < 2; ++mi) {
        int r = mi * 16 + rlo;
        kb[mi] = (r < 19) ? CL_RD(g19 + r, 64 + ks * 32 + rhi * 8) : z8;
        qa[mi] = (r < 19) ? CL_RD(g19 + r, ks * 32 + rhi * 8) : z8;
      }
#pragma unroll
      for (int mi = 0; mi < 2; ++mi)
#pragma unroll
        for (int nj = 0; nj < 2; ++nj)
          s[mi][nj] = __builtin_amdgcn_mfma_f32_16x16x32_bf16(kb[mi], qa[nj], s[mi][nj], 0, 0, 0);
    }
    // lane view: q = nj*16 + rlo; k = mi*16 + rhi*4 + j
#pragma unroll
    for (int nj = 0; nj < 2; ++nj) {
      const int q = nj * 16 + rlo;
      const bool qv = (q < 19);
      const bool wv = (rhi == 0);          // k=16..18 live on rhi==0 (j<3)
      float v0 = s[0][nj][0] * 0.125f;
      float v1 = s[0][nj][1] * 0.125f;
      float v2 = s[0][nj][2] * 0.125f;
      float v3 = s[0][nj][3] * 0.125f;
      float w0 = s[1][nj][0] * 0.125f;
      float w1 = s[1][nj][1] * 0.125f;
      float w2 = s[1][nj][2] * 0.125f;
      float mm = fmaxf(fmaxf(v0, v1), fmaxf(v2, v3));
      if (wv) mm = fmaxf(mm, fmaxf(fmaxf(w0, w1), w2));
      mm = fmaxf(mm, __shfl_xor(mm, 16));
      mm = fmaxf(mm, __shfl_xor(mm, 32));
      float e0 = __expf(v0 - mm), e1 = __expf(v1 - mm);
      float e2 = __expf(v2 - mm), e3 = __expf(v3 - mm);
      float se = e0 + e1 + e2 + e3;
      int k0 = rhi * 4;
      float ue = ((k0 > q) ? e0 : 0.f) + ((k0 + 1 > q) ? e1 : 0.f)
               + ((k0 + 2 > q) ? e2 : 0.f) + ((k0 + 3 > q) ? e3 : 0.f);
      if (wv) {
        float f0 = __expf(w0 - mm), f1 = __expf(w1 - mm), f2 = __expf(w2 - mm);
        se += f0 + f1 + f2;
        ue += ((16 > q) ? f0 : 0.f) + ((17 > q) ? f1 : 0.f) + ((18 > q) ? f2 : 0.f);
      }
      se += __shfl_xor(se, 16); se += __shfl_xor(se, 32);
      ue += __shfl_xor(ue, 16); ue += __shfl_xor(ue, 32);
      if (qv && rhi == 0) psum += ue / se;
    }
  }

  psum += __shfl_xor(psum, 1);
  psum += __shfl_xor(psum, 2);
  psum += __shfl_xor(psum, 4);
  psum += __shfl_xor(psum, 8);
  psum += __shfl_xor(psum, 16);
  psum += __shfl_xor(psum, 32);
  if (lane == 0) red[wid] = psum;
  __syncthreads();
  if (tid == 0) {
    // all 8 groups of this block share batch b = (hb*8)/512 = hb>>6
    atomicAdd(&oacc[hb >> 6], red[0] + red[1] + red[2] + red[3]
                            + red[4] + red[5] + red[6] + red[7]);
  }
}

// ---------- kernel: finalize out[b] = clip(acc[b] / (8*171*512), 0, 1) ----------
__global__ void k_fin(const float* __restrict__ acc, float* __restrict__ out) {
  int t = threadIdx.x;
  if (t < 16) {
    float v = acc[t] * (1.0f / 700416.0f);
    out[t] = fminf(1.0f, fmaxf(0.0f, v));
  }
}

// ---------- host ----------
extern "C" void kernel_launch(void* const* d_in, const int* in_sizes, int n_in,
                              void* d_out, int out_size, void* d_ws, size_t ws_size,
                              hipStream_t stream) {
  const float* eeg = (const float*)d_in[0];
  const float* wq  = (const float*)d_in[1];
  const float* wk  = (const float*)d_in[2];
  const float* bq  = (const float*)d_in[3];
  const float* bk  = (const float*)d_in[4];
  float* out = (float*)d_out;

  char* ws = (char*)d_ws;
  unsigned short* Wf  = (unsigned short*)ws;                       // 1 MiB weights
  float* acc          = (float*)(ws + (1 << 20));                  // 64 B accumulators
  unsigned short* Afb = (unsigned short*)(ws + (1 << 20) + 256);   // 167.8 MB frag eeg

  hipMemsetAsync(acc, 0, 64, stream);
  k_convw<<<256, 256, 0, stream>>>(wq, wk, Wf);
  k_conva<<<40960, 256, 0, stream>>>(eeg, Afb);   // 1024 hb x 10 f x 16 kt frags
  k_fgemm<<<8192, 512, 0, stream>>>(Afb, Wf, bq, bk, acc);
  k_fin<<<1, 64, 0, stream>>>(acc, out);
}